// Round 8
// baseline (332.015 us; speedup 1.0000x reference)
//
#include <hip/hip_runtime.h>
#include <math.h>

typedef _Float16 half4v __attribute__((ext_vector_type(4)));
typedef _Float16 half8v __attribute__((ext_vector_type(8)));
typedef float f32x4 __attribute__((ext_vector_type(4)));

// ------------- setup: zero cnt8 + convert/transpose W0,W1 to fp16 -------------

__global__ void setup_kernel(const float* __restrict__ W0, const float* __restrict__ W1,
                             _Float16* __restrict__ Wt0, _Float16* __restrict__ Wt1,
                             int4* __restrict__ cnt, int n4) {
    int gid = blockIdx.x * 256 + threadIdx.x;
    if (gid < 32768) {            // 2 matrices x 16384 elems: Wt[n][k] = (fp16)W[k][n]
        int m = gid >> 14;
        int rem = gid & 16383;
        int n = rem >> 7, k = rem & 127;
        const float* W = m ? W1 : W0;
        _Float16* Wt = m ? Wt1 : Wt0;
        Wt[n * 128 + k] = (_Float16)W[k * 128 + n];
    }
    int stride = gridDim.x * 256;
    for (int i = gid; i < n4; i += stride) cnt[i] = make_int4(0, 0, 0, 0);
}

// Privatized degree histogram: copy = blockIdx&7 -> XCD-local atomics.
__global__ void count_kernel(const int* __restrict__ ei, int* __restrict__ cnt8,
                             int N, int E) {
    int e = blockIdx.x * 256 + threadIdx.x;
    int copy = blockIdx.x & 7;
    if (e < E) atomicAdd(&cnt8[(size_t)copy * N + ei[e]], 1);
}

// exclusive scan of deg -> excl; sums 8 histogram copies; dis = rsqrt(deg+1)
__global__ void scan1_kernel(const int* __restrict__ cnt8, int* __restrict__ excl,
                             int* __restrict__ blksum, float* __restrict__ dis,
                             int N) {
    __shared__ int sdata[256];
    int t = threadIdx.x;
    int base = blockIdx.x * 1024 + t * 4;
    int v0 = 0, v1 = 0, v2 = 0, v3 = 0;
#pragma unroll
    for (int k = 0; k < 8; ++k) {
        const int* c = cnt8 + (size_t)k * N;
        if (base + 0 < N) v0 += c[base + 0];
        if (base + 1 < N) v1 += c[base + 1];
        if (base + 2 < N) v2 += c[base + 2];
        if (base + 3 < N) v3 += c[base + 3];
    }
    if (base + 0 < N) dis[base + 0] = rsqrtf((float)v0 + 1.0f);
    if (base + 1 < N) dis[base + 1] = rsqrtf((float)v1 + 1.0f);
    if (base + 2 < N) dis[base + 2] = rsqrtf((float)v2 + 1.0f);
    if (base + 3 < N) dis[base + 3] = rsqrtf((float)v3 + 1.0f);
    int tot = v0 + v1 + v2 + v3;
    sdata[t] = tot;
    __syncthreads();
    for (int o = 1; o < 256; o <<= 1) {
        int x = (t >= o) ? sdata[t - o] : 0;
        __syncthreads();
        sdata[t] += x;
        __syncthreads();
    }
    int incl = sdata[t];
    int eb = incl - tot;
    if (base + 0 < N) excl[base + 0] = eb;
    if (base + 1 < N) excl[base + 1] = eb + v0;
    if (base + 2 < N) excl[base + 2] = eb + v0 + v1;
    if (base + 3 < N) excl[base + 3] = eb + v0 + v1 + v2;
    if (t == 255) blksum[blockIdx.x] = incl;
}

// scan2 fused: every block redoes the <=64-elem blksum exclusive scan locally.
__global__ void scan23_kernel(int* __restrict__ excl, int* __restrict__ cursor,
                              const int* __restrict__ blksum, int nb, int N, int E) {
    __shared__ int sblk[64];
    int t = threadIdx.x;
    if (t < 64) {
        int orig = (t < nb) ? blksum[t] : 0;
        int v = orig;
        for (int o = 1; o < 64; o <<= 1) { int x = __shfl_up(v, o); if (t >= o) v += x; }
        sblk[t] = v - orig;
    }
    __syncthreads();
    int i = blockIdx.x * 256 + t;
    if (i < N) {
        int v = excl[i] + sblk[i >> 10];
        excl[i] = v;
        cursor[i] = v;
    }
    if (i == 0) excl[N] = E;
}

// XCD-partitioned CSR fill (part = blockIdx&7 owns one dest range).
__global__ void fill_kernel(const int* __restrict__ ei, int E, int PART,
                            int* __restrict__ cursor, int* __restrict__ csr_col) {
    int part = blockIdx.x & 7;
    int e = (blockIdx.x >> 3) * 256 + threadIdx.x;
    if (e >= E) return;
    int r = ei[e];
    int lo = part * PART;
    if (r < lo || r >= lo + PART) return;
    int c = ei[E + e];
    int pos = atomicAdd(&cursor[r], 1);
    csr_col[pos] = c;
}

// -------- MFMA GEMM: out16[N][128] = fp16( x[N][128](f32) @ W0 ) --------

__global__ __launch_bounds__(256) void gemm_mfma_f32(const float* __restrict__ A,
                                                     const _Float16* __restrict__ Wt,
                                                     _Float16* __restrict__ out, int N) {
    __shared__ _Float16 smem[128 * 136];    // sWt, reused as sOut in epilogue
    _Float16* sWt = smem;
    _Float16* sOut = smem;
    const int t = threadIdx.x;
    const int w = t >> 6, l = t & 63;
    const int l15 = l & 15, kgrp = l >> 4;
    const int brow = blockIdx.x * 64;

#pragma unroll
    for (int i = 0; i < 8; ++i) {
        int g = t + i * 256;
        int n = g >> 4, kg = g & 15;
        *(half8v*)&sWt[n * 136 + kg * 8] = *(const half8v*)&Wt[n * 128 + kg * 8];
    }
    __syncthreads();

    int arow = brow + w * 16 + l15;
    f32x4 acc[8];
#pragma unroll
    for (int ct = 0; ct < 8; ++ct) acc[ct] = (f32x4){0.f, 0.f, 0.f, 0.f};

#pragma unroll
    for (int kt = 0; kt < 4; ++kt) {
        int kb = kt * 32 + kgrp * 8;
        half8v af;
        if (arow < N) {
            float4 x0 = *(const float4*)&A[(size_t)arow * 128 + kb];
            float4 x1 = *(const float4*)&A[(size_t)arow * 128 + kb + 4];
            af = (half8v){(_Float16)x0.x, (_Float16)x0.y, (_Float16)x0.z, (_Float16)x0.w,
                          (_Float16)x1.x, (_Float16)x1.y, (_Float16)x1.z, (_Float16)x1.w};
        } else af = (half8v)0;
#pragma unroll
        for (int ct = 0; ct < 8; ++ct) {
            half8v bf = *(const half8v*)&sWt[(ct * 16 + l15) * 136 + kb];
            acc[ct] = __builtin_amdgcn_mfma_f32_16x16x32_f16(af, bf, acc[ct], 0, 0, 0);
        }
    }
    __syncthreads();

    // C/D layout: col = lane&15, row = (lane>>4)*4 + reg
#pragma unroll
    for (int ct = 0; ct < 8; ++ct) {
#pragma unroll
        for (int r = 0; r < 4; ++r) {
            sOut[(w * 16 + kgrp * 4 + r) * 136 + ct * 16 + l15] = (_Float16)acc[ct][r];
        }
    }
    __syncthreads();

#pragma unroll
    for (int i = 0; i < 4; ++i) {
        int g = t + i * 256;
        int row = g >> 4, c16 = g & 15;
        int grow = brow + row;
        if (grow < N)
            *(half8v*)&out[(size_t)grow * 128 + c16 * 8] =
                *(const half8v*)&sOut[row * 136 + c16 * 8];
    }
}

// ---- fused: agg(relu(gather(tbl)+bias)) for 64 rows -> LDS -> MFMA @ Wt ----
// Saves the 25.6MB intermediate roundtrip between agg1 and gemm1.

__global__ __launch_bounds__(256) void agg_gemm1(const _Float16* __restrict__ tbl,
        const int* __restrict__ csr_col, const int* __restrict__ offset,
        const float* __restrict__ dis, const float* __restrict__ bias,
        const _Float16* __restrict__ Wt, _Float16* __restrict__ out, int N) {
    __shared__ _Float16 sWt[128 * 136];   // 34816 B, reused as sOut
    __shared__ _Float16 sAgg[64 * 136];   // 17408 B
    const int t = threadIdx.x;
    const int w = t >> 6, l = t & 63;
    const int l15 = l & 15, kgrp = l >> 4;
    const int brow = blockIdx.x * 64;

    // stage Wt; latency hidden under the agg phase (one barrier before MFMA)
#pragma unroll
    for (int i = 0; i < 8; ++i) {
        int g = t + i * 256;
        int n = g >> 4, kg = g & 15;
        *(half8v*)&sWt[n * 136 + kg * 8] = *(const half8v*)&Wt[n * 128 + kg * 8];
    }

    // agg phase: wave w aggregates nodes brow+w*16 .. +15 into sAgg (wave-local)
    int half = l >> 5;
    int col4 = (l & 31) * 4;
    for (int i = 0; i < 16; ++i) {
        int node = brow + w * 16 + i;
        if (node >= N) break;            // wave-uniform
        float dn = dis[node];
        half4v sv = *(const half4v*)&tbl[(size_t)node * 128 + col4];
        float sw = half ? 0.0f : dn * dn;
        float4 acc;
        acc.x = sw * (float)sv.x; acc.y = sw * (float)sv.y;
        acc.z = sw * (float)sv.z; acc.w = sw * (float)sv.w;
        int s = offset[node], e = offset[node + 1];
        int j = s + half;
        for (; j + 6 < e; j += 8) {
            int c0 = csr_col[j];
            int c1 = csr_col[j + 2];
            int c2 = csr_col[j + 4];
            int c3 = csr_col[j + 6];
            half4v v0 = *(const half4v*)&tbl[(size_t)c0 * 128 + col4];
            half4v v1 = *(const half4v*)&tbl[(size_t)c1 * 128 + col4];
            half4v v2 = *(const half4v*)&tbl[(size_t)c2 * 128 + col4];
            half4v v3 = *(const half4v*)&tbl[(size_t)c3 * 128 + col4];
            float w0 = dn * dis[c0];
            float w1 = dn * dis[c1];
            float w2 = dn * dis[c2];
            float w3 = dn * dis[c3];
            acc.x = fmaf(w0, (float)v0.x, acc.x); acc.y = fmaf(w0, (float)v0.y, acc.y);
            acc.z = fmaf(w0, (float)v0.z, acc.z); acc.w = fmaf(w0, (float)v0.w, acc.w);
            acc.x = fmaf(w1, (float)v1.x, acc.x); acc.y = fmaf(w1, (float)v1.y, acc.y);
            acc.z = fmaf(w1, (float)v1.z, acc.z); acc.w = fmaf(w1, (float)v1.w, acc.w);
            acc.x = fmaf(w2, (float)v2.x, acc.x); acc.y = fmaf(w2, (float)v2.y, acc.y);
            acc.z = fmaf(w2, (float)v2.z, acc.z); acc.w = fmaf(w2, (float)v2.w, acc.w);
            acc.x = fmaf(w3, (float)v3.x, acc.x); acc.y = fmaf(w3, (float)v3.y, acc.y);
            acc.z = fmaf(w3, (float)v3.z, acc.z); acc.w = fmaf(w3, (float)v3.w, acc.w);
        }
        for (; j < e; j += 2) {
            int c = csr_col[j];
            half4v v = *(const half4v*)&tbl[(size_t)c * 128 + col4];
            float wt = dn * dis[c];
            acc.x = fmaf(wt, (float)v.x, acc.x); acc.y = fmaf(wt, (float)v.y, acc.y);
            acc.z = fmaf(wt, (float)v.z, acc.z); acc.w = fmaf(wt, (float)v.w, acc.w);
        }
        acc.x += __shfl_xor(acc.x, 32);
        acc.y += __shfl_xor(acc.y, 32);
        acc.z += __shfl_xor(acc.z, 32);
        acc.w += __shfl_xor(acc.w, 32);
        if (half == 0) {
            float4 b = *(const float4*)&bias[col4];
            float ox = fmaxf(acc.x + b.x, 0.f), oy = fmaxf(acc.y + b.y, 0.f);
            float oz = fmaxf(acc.z + b.z, 0.f), ow = fmaxf(acc.w + b.w, 0.f);
            half4v o = {(_Float16)ox, (_Float16)oy, (_Float16)oz, (_Float16)ow};
            *(half4v*)&sAgg[(w * 16 + i) * 136 + col4] = o;
        }
    }
    __syncthreads();   // sWt staged; sAgg rows are wave-local

    f32x4 acc8[8];
#pragma unroll
    for (int ct = 0; ct < 8; ++ct) acc8[ct] = (f32x4){0.f, 0.f, 0.f, 0.f};
#pragma unroll
    for (int kt = 0; kt < 4; ++kt) {
        int kb = kt * 32 + kgrp * 8;
        half8v af = *(const half8v*)&sAgg[(w * 16 + l15) * 136 + kb];
#pragma unroll
        for (int ct = 0; ct < 8; ++ct) {
            half8v bf = *(const half8v*)&sWt[(ct * 16 + l15) * 136 + kb];
            acc8[ct] = __builtin_amdgcn_mfma_f32_16x16x32_f16(af, bf, acc8[ct], 0, 0, 0);
        }
    }
    __syncthreads();   // all sWt reads done -> reuse as sOut
    _Float16* sOut = sWt;
#pragma unroll
    for (int ct = 0; ct < 8; ++ct) {
#pragma unroll
        for (int r = 0; r < 4; ++r) {
            sOut[(w * 16 + kgrp * 4 + r) * 136 + ct * 16 + l15] = (_Float16)acc8[ct][r];
        }
    }
    __syncthreads();
#pragma unroll
    for (int i = 0; i < 4; ++i) {
        int g = t + i * 256;
        int row = g >> 4, c16 = g & 15;
        int grow = brow + row;
        if (grow < N)
            *(half8v*)&out[(size_t)grow * 128 + c16 * 8] =
                *(const half8v*)&sOut[row * 136 + c16 * 8];
    }
}

// ---- fused: agg(relu(gather(tbl)+bias)) for 64 rows -> LDS(f32) -> @W2 ----

__global__ __launch_bounds__(256) void agg_gemm16(const _Float16* __restrict__ tbl,
        const int* __restrict__ csr_col, const int* __restrict__ offset,
        const float* __restrict__ dis, const float* __restrict__ bias,
        const float* __restrict__ W2, float* __restrict__ t2, int N) {
    __shared__ float sW2[128 * 16];     // 8192 B
    __shared__ float sAggF[64 * 132];   // 33792 B
    const int t = threadIdx.x;
    const int w = t >> 6, l = t & 63;
    const int brow = blockIdx.x * 64;

#pragma unroll
    for (int i = 0; i < 2; ++i) {
        int idx = t + i * 256;          // 512 float4s = 2048 floats
        *(float4*)&sW2[idx * 4] = *(const float4*)&W2[idx * 4];
    }

    int half = l >> 5;
    int col4 = (l & 31) * 4;
    for (int i = 0; i < 16; ++i) {
        int node = brow + w * 16 + i;
        if (node >= N) break;
        float dn = dis[node];
        half4v sv = *(const half4v*)&tbl[(size_t)node * 128 + col4];
        float sw = half ? 0.0f : dn * dn;
        float4 acc;
        acc.x = sw * (float)sv.x; acc.y = sw * (float)sv.y;
        acc.z = sw * (float)sv.z; acc.w = sw * (float)sv.w;
        int s = offset[node], e = offset[node + 1];
        int j = s + half;
        for (; j + 6 < e; j += 8) {
            int c0 = csr_col[j];
            int c1 = csr_col[j + 2];
            int c2 = csr_col[j + 4];
            int c3 = csr_col[j + 6];
            half4v v0 = *(const half4v*)&tbl[(size_t)c0 * 128 + col4];
            half4v v1 = *(const half4v*)&tbl[(size_t)c1 * 128 + col4];
            half4v v2 = *(const half4v*)&tbl[(size_t)c2 * 128 + col4];
            half4v v3 = *(const half4v*)&tbl[(size_t)c3 * 128 + col4];
            float w0 = dn * dis[c0];
            float w1 = dn * dis[c1];
            float w2 = dn * dis[c2];
            float w3 = dn * dis[c3];
            acc.x = fmaf(w0, (float)v0.x, acc.x); acc.y = fmaf(w0, (float)v0.y, acc.y);
            acc.z = fmaf(w0, (float)v0.z, acc.z); acc.w = fmaf(w0, (float)v0.w, acc.w);
            acc.x = fmaf(w1, (float)v1.x, acc.x); acc.y = fmaf(w1, (float)v1.y, acc.y);
            acc.z = fmaf(w1, (float)v1.z, acc.z); acc.w = fmaf(w1, (float)v1.w, acc.w);
            acc.x = fmaf(w2, (float)v2.x, acc.x); acc.y = fmaf(w2, (float)v2.y, acc.y);
            acc.z = fmaf(w2, (float)v2.z, acc.z); acc.w = fmaf(w2, (float)v2.w, acc.w);
            acc.x = fmaf(w3, (float)v3.x, acc.x); acc.y = fmaf(w3, (float)v3.y, acc.y);
            acc.z = fmaf(w3, (float)v3.z, acc.z); acc.w = fmaf(w3, (float)v3.w, acc.w);
        }
        for (; j < e; j += 2) {
            int c = csr_col[j];
            half4v v = *(const half4v*)&tbl[(size_t)c * 128 + col4];
            float wt = dn * dis[c];
            acc.x = fmaf(wt, (float)v.x, acc.x); acc.y = fmaf(wt, (float)v.y, acc.y);
            acc.z = fmaf(wt, (float)v.z, acc.z); acc.w = fmaf(wt, (float)v.w, acc.w);
        }
        acc.x += __shfl_xor(acc.x, 32);
        acc.y += __shfl_xor(acc.y, 32);
        acc.z += __shfl_xor(acc.z, 32);
        acc.w += __shfl_xor(acc.w, 32);
        if (half == 0) {
            float4 b = *(const float4*)&bias[col4];
            float4 o;
            o.x = fmaxf(acc.x + b.x, 0.f); o.y = fmaxf(acc.y + b.y, 0.f);
            o.z = fmaxf(acc.z + b.z, 0.f); o.w = fmaxf(acc.w + b.w, 0.f);
            *(float4*)&sAggF[(w * 16 + i) * 132 + col4] = o;
        }
    }
    __syncthreads();

    // GEMM 128->16: 4 threads per row, 4 cols each
    int r = t >> 2;
    int c4g = (t & 3) * 4;
    float4 av = make_float4(0.f, 0.f, 0.f, 0.f);
    for (int k = 0; k < 128; ++k) {
        float a = sAggF[r * 132 + k];
        float4 wv = *(const float4*)&sW2[k * 16 + c4g];
        av.x = fmaf(a, wv.x, av.x); av.y = fmaf(a, wv.y, av.y);
        av.z = fmaf(a, wv.z, av.z); av.w = fmaf(a, wv.w, av.w);
    }
    int g = brow + r;
    if (g < N) *(float4*)&t2[(size_t)g * 16 + c4g] = av;
}

// ------- aggregation (16 wide) + bias + log_softmax: 16 lanes per node -------

__global__ __launch_bounds__(256) void agg16_ls_kernel(const float* __restrict__ t2,
        const int* __restrict__ csr_col,
        const int* __restrict__ offset, const float* __restrict__ dis,
        const float* __restrict__ b2, float* __restrict__ out, int N) {
    int gid = blockIdx.x * 256 + threadIdx.x;
    int node = gid >> 4;
    int c = gid & 15;
    if (node >= N) return;
    float dn = dis[node];
    float acc = dn * dn * t2[(size_t)node * 16 + c];
    int s = offset[node], e = offset[node + 1];
    for (int j = s; j < e; ++j) {
        int col = csr_col[j];
        float w = dn * dis[col];
        acc = fmaf(w, t2[(size_t)col * 16 + c], acc);
    }
    float v = acc + b2[c];
    float m = v;
#pragma unroll
    for (int o = 1; o < 16; o <<= 1) m = fmaxf(m, __shfl_xor(m, o, 16));
    float ex = expf(v - m);
    float ssum = ex;
#pragma unroll
    for (int o = 1; o < 16; o <<= 1) ssum += __shfl_xor(ssum, o, 16);
    out[(size_t)node * 16 + c] = v - m - logf(ssum);
}

// ---------------------------------- launch ----------------------------------

extern "C" void kernel_launch(void* const* d_in, const int* in_sizes, int n_in,
                              void* d_out, int out_size, void* d_ws, size_t ws_size,
                              hipStream_t stream) {
    const float* x  = (const float*)d_in[0];
    const int*   ei = (const int*)d_in[1];
    const float* W0 = (const float*)d_in[2];
    const float* b0 = (const float*)d_in[3];
    const float* W1 = (const float*)d_in[4];
    const float* b1 = (const float*)d_in[5];
    const float* W2 = (const float*)d_in[6];
    const float* b2 = (const float*)d_in[7];
    int N = in_sizes[0] / 128;
    int E = in_sizes[1] / 2;
    int PART = (N + 7) / 8;
    float* out = (float*)d_out;

    char* ws = (char*)d_ws;
    size_t off = 0;
    auto alloc = [&](size_t bytes) -> void* {
        void* p = ws + off;
        off = (off + bytes + 255) & ~(size_t)255;
        return p;
    };
    _Float16* t16  = (_Float16*)alloc((size_t)N * 128 * 2);
    _Float16* t16b = (_Float16*)alloc((size_t)N * 128 * 2);
    float* t2      = (float*)alloc((size_t)N * 16 * 4);
    int*   cnt8    = (int*)alloc((size_t)N * 8 * 4);
    int*   offs    = (int*)alloc((size_t)(N + 1) * 4);
    int*   cursor  = (int*)alloc((size_t)N * 4);
    int*   blksum  = (int*)alloc(64 * 4);
    float* dis     = (float*)alloc((size_t)N * 4);
    int*   csr_col = (int*)alloc((size_t)E * 4);
    _Float16* Wt0  = (_Float16*)alloc(128 * 128 * 2);
    _Float16* Wt1  = (_Float16*)alloc(128 * 128 * 2);

    int n4 = (int)(((size_t)N * 8) / 4);
    setup_kernel<<<400, 256, 0, stream>>>(W0, W1, Wt0, Wt1, (int4*)cnt8, n4);

    int nchunk = (E + 255) / 256;
    int nb = (N + 1023) / 1024;   // 49 for N=50000 (must be <= 64)
    count_kernel<<<nchunk, 256, 0, stream>>>(ei, cnt8, N, E);
    scan1_kernel<<<nb, 256, 0, stream>>>(cnt8, offs, blksum, dis, N);
    scan23_kernel<<<(N + 255) / 256, 256, 0, stream>>>(offs, cursor, blksum, nb, N, E);
    fill_kernel<<<nchunk * 8, 256, 0, stream>>>(ei, E, PART, cursor, csr_col);

    int blocks64 = (N + 63) / 64;

    gemm_mfma_f32<<<blocks64, 256, 0, stream>>>(x, Wt0, t16, N);
    agg_gemm1<<<blocks64, 256, 0, stream>>>(t16, csr_col, offs, dis, b0, Wt1, t16b, N);
    agg_gemm16<<<blocks64, 256, 0, stream>>>(t16b, csr_col, offs, dis, b1, W2, t2, N);
    agg16_ls_kernel<<<(int)(((size_t)N * 16 + 255) / 256), 256, 0, stream>>>(
        t2, csr_col, offs, dis, b2, out, N);
}

// Round 9
// 248.523 us; speedup vs baseline: 1.3360x; 1.3360x over previous
//
#include <hip/hip_runtime.h>
#include <math.h>

typedef _Float16 half2v __attribute__((ext_vector_type(2)));
typedef _Float16 half4v __attribute__((ext_vector_type(4)));
typedef _Float16 half8v __attribute__((ext_vector_type(8)));
typedef float f32x4 __attribute__((ext_vector_type(4)));

// ------------- setup: zero cnt8 + convert/transpose W0,W1 to fp16 -------------

__global__ void setup_kernel(const float* __restrict__ W0, const float* __restrict__ W1,
                             _Float16* __restrict__ Wt0, _Float16* __restrict__ Wt1,
                             int4* __restrict__ cnt, int n4) {
    int gid = blockIdx.x * 256 + threadIdx.x;
    if (gid < 32768) {            // 2 matrices x 16384 elems: Wt[n][k] = (fp16)W[k][n]
        int m = gid >> 14;
        int rem = gid & 16383;
        int n = rem >> 7, k = rem & 127;
        const float* W = m ? W1 : W0;
        _Float16* Wt = m ? Wt1 : Wt0;
        Wt[n * 128 + k] = (_Float16)W[k * 128 + n];
    }
    int stride = gridDim.x * 256;
    for (int i = gid; i < n4; i += stride) cnt[i] = make_int4(0, 0, 0, 0);
}

// Privatized degree histogram: copy = blockIdx&7 -> XCD-local atomics.
__global__ void count_kernel(const int* __restrict__ ei, int* __restrict__ cnt8,
                             int N, int E) {
    int e = blockIdx.x * 256 + threadIdx.x;
    int copy = blockIdx.x & 7;
    if (e < E) atomicAdd(&cnt8[(size_t)copy * N + ei[e]], 1);
}

// exclusive scan of deg -> excl; sums 8 histogram copies; dis = rsqrt(deg+1)
__global__ void scan1_kernel(const int* __restrict__ cnt8, int* __restrict__ excl,
                             int* __restrict__ blksum, float* __restrict__ dis,
                             int N) {
    __shared__ int sdata[256];
    int t = threadIdx.x;
    int base = blockIdx.x * 1024 + t * 4;
    int v0 = 0, v1 = 0, v2 = 0, v3 = 0;
#pragma unroll
    for (int k = 0; k < 8; ++k) {
        const int* c = cnt8 + (size_t)k * N;
        if (base + 0 < N) v0 += c[base + 0];
        if (base + 1 < N) v1 += c[base + 1];
        if (base + 2 < N) v2 += c[base + 2];
        if (base + 3 < N) v3 += c[base + 3];
    }
    if (base + 0 < N) dis[base + 0] = rsqrtf((float)v0 + 1.0f);
    if (base + 1 < N) dis[base + 1] = rsqrtf((float)v1 + 1.0f);
    if (base + 2 < N) dis[base + 2] = rsqrtf((float)v2 + 1.0f);
    if (base + 3 < N) dis[base + 3] = rsqrtf((float)v3 + 1.0f);
    int tot = v0 + v1 + v2 + v3;
    sdata[t] = tot;
    __syncthreads();
    for (int o = 1; o < 256; o <<= 1) {
        int x = (t >= o) ? sdata[t - o] : 0;
        __syncthreads();
        sdata[t] += x;
        __syncthreads();
    }
    int incl = sdata[t];
    int eb = incl - tot;
    if (base + 0 < N) excl[base + 0] = eb;
    if (base + 1 < N) excl[base + 1] = eb + v0;
    if (base + 2 < N) excl[base + 2] = eb + v0 + v1;
    if (base + 3 < N) excl[base + 3] = eb + v0 + v1 + v2;
    if (t == 255) blksum[blockIdx.x] = incl;
}

// scan2 fused: every block redoes the <=64-elem blksum exclusive scan locally.
__global__ void scan23_kernel(int* __restrict__ excl, int* __restrict__ cursor,
                              const int* __restrict__ blksum, int nb, int N, int E) {
    __shared__ int sblk[64];
    int t = threadIdx.x;
    if (t < 64) {
        int orig = (t < nb) ? blksum[t] : 0;
        int v = orig;
        for (int o = 1; o < 64; o <<= 1) { int x = __shfl_up(v, o); if (t >= o) v += x; }
        sblk[t] = v - orig;
    }
    __syncthreads();
    int i = blockIdx.x * 256 + t;
    if (i < N) {
        int v = excl[i] + sblk[i >> 10];
        excl[i] = v;
        cursor[i] = v;
    }
    if (i == 0) excl[N] = E;
}

// XCD-partitioned CSR fill (part = blockIdx&7 owns one dest range).
__global__ void fill_kernel(const int* __restrict__ ei, int E, int PART,
                            int* __restrict__ cursor, int* __restrict__ csr_col) {
    int part = blockIdx.x & 7;
    int e = (blockIdx.x >> 3) * 256 + threadIdx.x;
    if (e >= E) return;
    int r = ei[e];
    int lo = part * PART;
    if (r < lo || r >= lo + PART) return;
    int c = ei[E + e];
    int pos = atomicAdd(&cursor[r], 1);
    csr_col[pos] = c;
}

// -------- MFMA GEMM: out16[N][128] = fp16( A[N][128] @ W[128][128] ) --------
// Wt fp16 pre-transposed [n][k]; LDS staged padded (stride 136) for
// conflict-min ds_read_b128; epilogue reuses LDS for coalesced fp16 stores.

template <int AF32>
__global__ __launch_bounds__(256) void gemm_mfma(const void* __restrict__ Ain,
                                                 const _Float16* __restrict__ Wt,
                                                 _Float16* __restrict__ out, int N) {
    __shared__ _Float16 smem[128 * 136];    // 34816 B; aliased: sWt then sOut
    _Float16* sWt = smem;
    _Float16* sOut = smem;
    const int t = threadIdx.x;
    const int w = t >> 6, l = t & 63;
    const int l15 = l & 15, kgrp = l >> 4;
    const int brow = blockIdx.x * 64;

#pragma unroll
    for (int i = 0; i < 8; ++i) {
        int g = t + i * 256;
        int n = g >> 4, kg = g & 15;
        *(half8v*)&sWt[n * 136 + kg * 8] = *(const half8v*)&Wt[n * 128 + kg * 8];
    }
    __syncthreads();

    int arow = brow + w * 16 + l15;
    f32x4 acc[8];
#pragma unroll
    for (int ct = 0; ct < 8; ++ct) acc[ct] = (f32x4){0.f, 0.f, 0.f, 0.f};

#pragma unroll
    for (int kt = 0; kt < 4; ++kt) {
        int kb = kt * 32 + kgrp * 8;
        half8v af;
        if (AF32) {
            const float* A = (const float*)Ain;
            if (arow < N) {
                float4 x0 = *(const float4*)&A[(size_t)arow * 128 + kb];
                float4 x1 = *(const float4*)&A[(size_t)arow * 128 + kb + 4];
                af = (half8v){(_Float16)x0.x, (_Float16)x0.y, (_Float16)x0.z, (_Float16)x0.w,
                              (_Float16)x1.x, (_Float16)x1.y, (_Float16)x1.z, (_Float16)x1.w};
            } else af = (half8v)0;
        } else {
            const _Float16* A = (const _Float16*)Ain;
            af = (arow < N) ? *(const half8v*)&A[(size_t)arow * 128 + kb] : (half8v)0;
        }
#pragma unroll
        for (int ct = 0; ct < 8; ++ct) {
            half8v bf = *(const half8v*)&sWt[(ct * 16 + l15) * 136 + kb];
            acc[ct] = __builtin_amdgcn_mfma_f32_16x16x32_f16(af, bf, acc[ct], 0, 0, 0);
        }
    }
    __syncthreads();   // all sWt reads done; reuse LDS as sOut

    // C/D layout: col = lane&15, row = (lane>>4)*4 + reg  [guide-verified]
#pragma unroll
    for (int ct = 0; ct < 8; ++ct) {
#pragma unroll
        for (int r = 0; r < 4; ++r) {
            sOut[(w * 16 + kgrp * 4 + r) * 136 + ct * 16 + l15] = (_Float16)acc[ct][r];
        }
    }
    __syncthreads();

#pragma unroll
    for (int i = 0; i < 4; ++i) {
        int g = t + i * 256;
        int row = g >> 4, c16 = g & 15;
        int grow = brow + row;
        if (grow < N)
            *(half8v*)&out[(size_t)grow * 128 + c16 * 8] =
                *(const half8v*)&sOut[row * 136 + c16 * 8];
    }
}

// -------- GEMM: out[N][16] = A16[N][128] @ W[128][16]  (VALU, A fp16) --------

__global__ __launch_bounds__(256) void gemm_nk16(const _Float16* __restrict__ A,
                                                 const float* __restrict__ W,
                                                 float* __restrict__ out, int N) {
    __shared__ float sW[128][16];    // 8 KB
    __shared__ float sA[32][132];    // padded, 16.5 KB
    int t = threadIdx.x;
#pragma unroll
    for (int i = 0; i < 2; ++i) {
        int idx = t + i * 256;
        *(float4*)&sW[idx >> 2][(idx & 3) * 4] = *(const float4*)&W[idx * 4];
    }
    int brow = blockIdx.x * 32;
#pragma unroll
    for (int i = 0; i < 2; ++i) {
        int g = t + i * 256;         // 512 granules of 8 fp16
        int rr = g >> 4, c8 = g & 15;
        int grow = brow + rr;
        half8v v = (half8v)0;
        if (grow < N) v = *(const half8v*)&A[(size_t)grow * 128 + c8 * 8];
        float4 f0 = make_float4((float)v.s0, (float)v.s1, (float)v.s2, (float)v.s3);
        float4 f1 = make_float4((float)v.s4, (float)v.s5, (float)v.s6, (float)v.s7);
        *(float4*)&sA[rr][c8 * 8] = f0;
        *(float4*)&sA[rr][c8 * 8 + 4] = f1;
    }
    __syncthreads();
    int r = t >> 3;
    int cg = t & 7;
    float a0 = 0.f, a1 = 0.f;
#pragma unroll
    for (int k = 0; k < 128; ++k) {
        float a = sA[r][k];
        float2 w = *(const float2*)&sW[k][cg * 2];
        a0 = fmaf(a, w.x, a0);
        a1 = fmaf(a, w.y, a1);
    }
    int g = brow + r;
    if (g < N) {
        out[(size_t)g * 16 + cg * 2 + 0] = a0;
        out[(size_t)g * 16 + cg * 2 + 1] = a1;
    }
}

// ----- aggregation (128 wide), 2-way feature-chunked for XCD L2 locality -----
// chunk = blockIdx&1: 64-col fp16 slice = exactly one 128B line per edge (no
// overfetch); under round-robin dispatch chunk 0 -> XCDs {0,2,4,6}, chunk 1 ->
// {1,3,5,7}, halving each XCD's gather working set (12.8 -> 6.4 MB vs 4MB L2).
// One node per wave; two 32-lane halves each gather a different edge (4B/lane).

__global__ __launch_bounds__(256) void agg128_kernel(const _Float16* __restrict__ tbl,
        const int* __restrict__ csr_col,
        const int* __restrict__ offset, const float* __restrict__ dis,
        const float* __restrict__ bias, _Float16* __restrict__ out, int N, int do_relu) {
    int chunk = blockIdx.x & 1;
    int node = (blockIdx.x >> 1) * 4 + (threadIdx.x >> 6);
    if (node >= N) return;
    int lane = threadIdx.x & 63;
    int half = lane >> 5;
    int colf = chunk * 64 + (lane & 31) * 2;   // 2 fp16 = 4B per lane
    float dn = dis[node];

    half2v sv = *(const half2v*)&tbl[(size_t)node * 128 + colf];
    float sw = half ? 0.0f : dn * dn;
    float2 acc;
    acc.x = sw * (float)sv.x; acc.y = sw * (float)sv.y;

    int s = offset[node], e = offset[node + 1];
    int j = s + half;                    // half 0: s, s+2,...; half 1: s+1, s+3,...
    for (; j + 6 < e; j += 8) {          // 8 edges per wave in flight
        int c0 = csr_col[j];
        int c1 = csr_col[j + 2];
        int c2 = csr_col[j + 4];
        int c3 = csr_col[j + 6];
        half2v v0 = *(const half2v*)&tbl[(size_t)c0 * 128 + colf];
        half2v v1 = *(const half2v*)&tbl[(size_t)c1 * 128 + colf];
        half2v v2 = *(const half2v*)&tbl[(size_t)c2 * 128 + colf];
        half2v v3 = *(const half2v*)&tbl[(size_t)c3 * 128 + colf];
        float w0 = dn * dis[c0];
        float w1 = dn * dis[c1];
        float w2 = dn * dis[c2];
        float w3 = dn * dis[c3];
        acc.x = fmaf(w0, (float)v0.x, acc.x); acc.y = fmaf(w0, (float)v0.y, acc.y);
        acc.x = fmaf(w1, (float)v1.x, acc.x); acc.y = fmaf(w1, (float)v1.y, acc.y);
        acc.x = fmaf(w2, (float)v2.x, acc.x); acc.y = fmaf(w2, (float)v2.y, acc.y);
        acc.x = fmaf(w3, (float)v3.x, acc.x); acc.y = fmaf(w3, (float)v3.y, acc.y);
    }
    for (; j < e; j += 2) {
        int c = csr_col[j];
        half2v v = *(const half2v*)&tbl[(size_t)c * 128 + colf];
        float w = dn * dis[c];
        acc.x = fmaf(w, (float)v.x, acc.x); acc.y = fmaf(w, (float)v.y, acc.y);
    }
    acc.x += __shfl_xor(acc.x, 32);
    acc.y += __shfl_xor(acc.y, 32);
    if (half == 0) {
        float2 b = *(const float2*)&bias[colf];
        float ox = acc.x + b.x, oy = acc.y + b.y;
        if (do_relu) { ox = fmaxf(ox, 0.f); oy = fmaxf(oy, 0.f); }
        half2v o = {(_Float16)ox, (_Float16)oy};
        *(half2v*)&out[(size_t)node * 128 + colf] = o;
    }
}

// ------- aggregation (16 wide) + bias + log_softmax: 16 lanes per node -------

__global__ __launch_bounds__(256) void agg16_ls_kernel(const float* __restrict__ t2,
        const int* __restrict__ csr_col,
        const int* __restrict__ offset, const float* __restrict__ dis,
        const float* __restrict__ b2, float* __restrict__ out, int N) {
    int gid = blockIdx.x * 256 + threadIdx.x;
    int node = gid >> 4;
    int c = gid & 15;
    if (node >= N) return;
    float dn = dis[node];
    float acc = dn * dn * t2[(size_t)node * 16 + c];
    int s = offset[node], e = offset[node + 1];
    for (int j = s; j < e; ++j) {
        int col = csr_col[j];
        float w = dn * dis[col];
        acc = fmaf(w, t2[(size_t)col * 16 + c], acc);
    }
    float v = acc + b2[c];
    float m = v;
#pragma unroll
    for (int o = 1; o < 16; o <<= 1) m = fmaxf(m, __shfl_xor(m, o, 16));
    float ex = expf(v - m);
    float ssum = ex;
#pragma unroll
    for (int o = 1; o < 16; o <<= 1) ssum += __shfl_xor(ssum, o, 16);
    out[(size_t)node * 16 + c] = v - m - logf(ssum);
}

// ---------------------------------- launch ----------------------------------

extern "C" void kernel_launch(void* const* d_in, const int* in_sizes, int n_in,
                              void* d_out, int out_size, void* d_ws, size_t ws_size,
                              hipStream_t stream) {
    const float* x  = (const float*)d_in[0];
    const int*   ei = (const int*)d_in[1];
    const float* W0 = (const float*)d_in[2];
    const float* b0 = (const float*)d_in[3];
    const float* W1 = (const float*)d_in[4];
    const float* b1 = (const float*)d_in[5];
    const float* W2 = (const float*)d_in[6];
    const float* b2 = (const float*)d_in[7];
    int N = in_sizes[0] / 128;
    int E = in_sizes[1] / 2;
    int PART = (N + 7) / 8;
    float* out = (float*)d_out;

    char* ws = (char*)d_ws;
    size_t off = 0;
    auto alloc = [&](size_t bytes) -> void* {
        void* p = ws + off;
        off = (off + bytes + 255) & ~(size_t)255;
        return p;
    };
    _Float16* t16  = (_Float16*)alloc((size_t)N * 128 * 2);
    _Float16* tB16 = (_Float16*)alloc((size_t)N * 128 * 2);
    float* t2      = (float*)alloc((size_t)N * 16 * 4);
    int*   cnt8    = (int*)alloc((size_t)N * 8 * 4);
    int*   offs    = (int*)alloc((size_t)(N + 1) * 4);
    int*   cursor  = (int*)alloc((size_t)N * 4);
    int*   blksum  = (int*)alloc(64 * 4);
    float* dis     = (float*)alloc((size_t)N * 4);
    int*   csr_col = (int*)alloc((size_t)E * 4);
    _Float16* Wt0  = (_Float16*)alloc(128 * 128 * 2);
    _Float16* Wt1  = (_Float16*)alloc(128 * 128 * 2);

    int n4 = (int)(((size_t)N * 8) / 4);
    setup_kernel<<<400, 256, 0, stream>>>(W0, W1, Wt0, Wt1, (int4*)cnt8, n4);

    int nchunk = (E + 255) / 256;
    int nb = (N + 1023) / 1024;   // 49 for N=50000 (must be <= 64)
    count_kernel<<<nchunk, 256, 0, stream>>>(ei, cnt8, N, E);
    scan1_kernel<<<nb, 256, 0, stream>>>(cnt8, offs, blksum, dis, N);
    scan23_kernel<<<(N + 255) / 256, 256, 0, stream>>>(offs, cursor, blksum, nb, N, E);
    fill_kernel<<<nchunk * 8, 256, 0, stream>>>(ei, E, PART, cursor, csr_col);

    int gemm_blocks = (N + 63) / 64;
    int agg_blocks  = ((N + 3) / 4) * 2;

    gemm_mfma<1><<<gemm_blocks, 256, 0, stream>>>(x, Wt0, t16, N);
    agg128_kernel<<<agg_blocks, 256, 0, stream>>>(t16, csr_col, offs, dis, b0, tB16, N, 1);
    gemm_mfma<0><<<gemm_blocks, 256, 0, stream>>>(tB16, Wt1, t16, N);
    agg128_kernel<<<agg_blocks, 256, 0, stream>>>(t16, csr_col, offs, dis, b1, tB16, N, 1);
    gemm_nk16<<<(N + 31) / 32, 256, 0, stream>>>(tB16, W2, t2, N);
    agg16_ls_kernel<<<(int)(((size_t)N * 16 + 255) / 256), 256, 0, stream>>>(
        t2, csr_col, offs, dis, b2, out, N);
}

// Round 10
// 214.332 us; speedup vs baseline: 1.5491x; 1.1595x over previous
//
#include <hip/hip_runtime.h>
#include <math.h>

typedef _Float16 half8v __attribute__((ext_vector_type(8)));
typedef float f32x4 __attribute__((ext_vector_type(4)));

// ------------- setup: zero cnt8 + convert/transpose W0,W1 to fp16 -------------

__global__ void setup_kernel(const float* __restrict__ W0, const float* __restrict__ W1,
                             _Float16* __restrict__ Wt0, _Float16* __restrict__ Wt1,
                             int4* __restrict__ cnt, int n4) {
    int gid = blockIdx.x * 256 + threadIdx.x;
    if (gid < 32768) {            // 2 matrices x 16384 elems: Wt[n][k] = (fp16)W[k][n]
        int m = gid >> 14;
        int rem = gid & 16383;
        int n = rem >> 7, k = rem & 127;
        const float* W = m ? W1 : W0;
        _Float16* Wt = m ? Wt1 : Wt0;
        Wt[n * 128 + k] = (_Float16)W[k * 128 + n];
    }
    int stride = gridDim.x * 256;
    for (int i = gid; i < n4; i += stride) cnt[i] = make_int4(0, 0, 0, 0);
}

// Privatized degree histogram: copy = blockIdx&7 -> XCD-local atomics.
__global__ void count_kernel(const int* __restrict__ ei, int* __restrict__ cnt8,
                             int N, int E) {
    int e = blockIdx.x * 256 + threadIdx.x;
    int copy = blockIdx.x & 7;
    if (e < E) atomicAdd(&cnt8[(size_t)copy * N + ei[e]], 1);
}

// exclusive scan of deg -> excl; sums 8 histogram copies; dis = rsqrt(deg+1)
__global__ void scan1_kernel(const int* __restrict__ cnt8, int* __restrict__ excl,
                             int* __restrict__ blksum, float* __restrict__ dis,
                             int N) {
    __shared__ int sdata[256];
    int t = threadIdx.x;
    int base = blockIdx.x * 1024 + t * 4;
    int v0 = 0, v1 = 0, v2 = 0, v3 = 0;
#pragma unroll
    for (int k = 0; k < 8; ++k) {
        const int* c = cnt8 + (size_t)k * N;
        if (base + 0 < N) v0 += c[base + 0];
        if (base + 1 < N) v1 += c[base + 1];
        if (base + 2 < N) v2 += c[base + 2];
        if (base + 3 < N) v3 += c[base + 3];
    }
    if (base + 0 < N) dis[base + 0] = rsqrtf((float)v0 + 1.0f);
    if (base + 1 < N) dis[base + 1] = rsqrtf((float)v1 + 1.0f);
    if (base + 2 < N) dis[base + 2] = rsqrtf((float)v2 + 1.0f);
    if (base + 3 < N) dis[base + 3] = rsqrtf((float)v3 + 1.0f);
    int tot = v0 + v1 + v2 + v3;
    sdata[t] = tot;
    __syncthreads();
    for (int o = 1; o < 256; o <<= 1) {
        int x = (t >= o) ? sdata[t - o] : 0;
        __syncthreads();
        sdata[t] += x;
        __syncthreads();
    }
    int incl = sdata[t];
    int eb = incl - tot;
    if (base + 0 < N) excl[base + 0] = eb;
    if (base + 1 < N) excl[base + 1] = eb + v0;
    if (base + 2 < N) excl[base + 2] = eb + v0 + v1;
    if (base + 3 < N) excl[base + 3] = eb + v0 + v1 + v2;
    if (t == 255) blksum[blockIdx.x] = incl;
}

// scan2 fused: every block redoes the <=64-elem blksum exclusive scan locally.
__global__ void scan23_kernel(int* __restrict__ excl, int* __restrict__ cursor,
                              const int* __restrict__ blksum, int nb, int N, int E) {
    __shared__ int sblk[64];
    int t = threadIdx.x;
    if (t < 64) {
        int orig = (t < nb) ? blksum[t] : 0;
        int v = orig;
        for (int o = 1; o < 64; o <<= 1) { int x = __shfl_up(v, o); if (t >= o) v += x; }
        sblk[t] = v - orig;
    }
    __syncthreads();
    int i = blockIdx.x * 256 + t;
    if (i < N) {
        int v = excl[i] + sblk[i >> 10];
        excl[i] = v;
        cursor[i] = v;
    }
    if (i == 0) excl[N] = E;
}

// XCD-partitioned CSR fill; stores packed {col, weight} per edge so the agg
// kernels get the weight with a single sequential 8B load (no random dis[c]).
__global__ void fill_kernel(const int* __restrict__ ei, int E, int PART,
                            int* __restrict__ cursor, const float* __restrict__ dis,
                            int2* __restrict__ csr_ew) {
    int part = blockIdx.x & 7;
    int e = (blockIdx.x >> 3) * 256 + threadIdx.x;
    if (e >= E) return;
    int r = ei[e];
    int lo = part * PART;
    if (r < lo || r >= lo + PART) return;
    int c = ei[E + e];
    float w = dis[r] * dis[c];
    int pos = atomicAdd(&cursor[r], 1);
    csr_ew[pos] = make_int2(c, __float_as_int(w));
}

// -------- MFMA GEMM: out16[N][128] = fp16( A[N][128] @ W[128][128] ) --------

template <int AF32>
__global__ __launch_bounds__(256) void gemm_mfma(const void* __restrict__ Ain,
                                                 const _Float16* __restrict__ Wt,
                                                 _Float16* __restrict__ out, int N) {
    __shared__ _Float16 smem[128 * 136];    // 34816 B; aliased: sWt then sOut
    _Float16* sWt = smem;
    _Float16* sOut = smem;
    const int t = threadIdx.x;
    const int w = t >> 6, l = t & 63;
    const int l15 = l & 15, kgrp = l >> 4;
    const int brow = blockIdx.x * 64;

#pragma unroll
    for (int i = 0; i < 8; ++i) {
        int g = t + i * 256;
        int n = g >> 4, kg = g & 15;
        *(half8v*)&sWt[n * 136 + kg * 8] = *(const half8v*)&Wt[n * 128 + kg * 8];
    }
    __syncthreads();

    int arow = brow + w * 16 + l15;
    f32x4 acc[8];
#pragma unroll
    for (int ct = 0; ct < 8; ++ct) acc[ct] = (f32x4){0.f, 0.f, 0.f, 0.f};

#pragma unroll
    for (int kt = 0; kt < 4; ++kt) {
        int kb = kt * 32 + kgrp * 8;
        half8v af;
        if (AF32) {
            const float* A = (const float*)Ain;
            if (arow < N) {
                float4 x0 = *(const float4*)&A[(size_t)arow * 128 + kb];
                float4 x1 = *(const float4*)&A[(size_t)arow * 128 + kb + 4];
                af = (half8v){(_Float16)x0.x, (_Float16)x0.y, (_Float16)x0.z, (_Float16)x0.w,
                              (_Float16)x1.x, (_Float16)x1.y, (_Float16)x1.z, (_Float16)x1.w};
            } else af = (half8v)0;
        } else {
            const _Float16* A = (const _Float16*)Ain;
            af = (arow < N) ? *(const half8v*)&A[(size_t)arow * 128 + kb] : (half8v)0;
        }
#pragma unroll
        for (int ct = 0; ct < 8; ++ct) {
            half8v bf = *(const half8v*)&sWt[(ct * 16 + l15) * 136 + kb];
            acc[ct] = __builtin_amdgcn_mfma_f32_16x16x32_f16(af, bf, acc[ct], 0, 0, 0);
        }
    }
    __syncthreads();

    // C/D layout: col = lane&15, row = (lane>>4)*4 + reg  [guide-verified]
#pragma unroll
    for (int ct = 0; ct < 8; ++ct) {
#pragma unroll
        for (int r = 0; r < 4; ++r) {
            sOut[(w * 16 + kgrp * 4 + r) * 136 + ct * 16 + l15] = (_Float16)acc[ct][r];
        }
    }
    __syncthreads();

#pragma unroll
    for (int i = 0; i < 4; ++i) {
        int g = t + i * 256;
        int row = g >> 4, c16 = g & 15;
        int grow = brow + row;
        if (grow < N)
            *(half8v*)&out[(size_t)grow * 128 + c16 * 8] =
                *(const half8v*)&sOut[row * 136 + c16 * 8];
    }
}

// -------- GEMM: out[N][16] = A16[N][128] @ W[128][16]  (VALU, A fp16) --------

__global__ __launch_bounds__(256) void gemm_nk16(const _Float16* __restrict__ A,
                                                 const float* __restrict__ W,
                                                 float* __restrict__ out, int N) {
    __shared__ float sW[128][16];    // 8 KB
    __shared__ float sA[32][132];    // padded, 16.5 KB
    int t = threadIdx.x;
#pragma unroll
    for (int i = 0; i < 2; ++i) {
        int idx = t + i * 256;
        *(float4*)&sW[idx >> 2][(idx & 3) * 4] = *(const float4*)&W[idx * 4];
    }
    int brow = blockIdx.x * 32;
#pragma unroll
    for (int i = 0; i < 2; ++i) {
        int g = t + i * 256;         // 512 granules of 8 fp16
        int rr = g >> 4, c8 = g & 15;
        int grow = brow + rr;
        half8v v = (half8v)0;
        if (grow < N) v = *(const half8v*)&A[(size_t)grow * 128 + c8 * 8];
        float4 f0 = make_float4((float)v.s0, (float)v.s1, (float)v.s2, (float)v.s3);
        float4 f1 = make_float4((float)v.s4, (float)v.s5, (float)v.s6, (float)v.s7);
        *(float4*)&sA[rr][c8 * 8] = f0;
        *(float4*)&sA[rr][c8 * 8 + 4] = f1;
    }
    __syncthreads();
    int r = t >> 3;
    int cg = t & 7;
    float a0 = 0.f, a1 = 0.f;
#pragma unroll
    for (int k = 0; k < 128; ++k) {
        float a = sA[r][k];
        float2 w = *(const float2*)&sW[k][cg * 2];
        a0 = fmaf(a, w.x, a0);
        a1 = fmaf(a, w.y, a1);
    }
    int g = brow + r;
    if (g < N) {
        out[(size_t)g * 16 + cg * 2 + 0] = a0;
        out[(size_t)g * 16 + cg * 2 + 1] = a1;
    }
}

// ----- aggregation (128 wide): one node/wave, 4 groups of 16 lanes, each
// group gathers a whole 256B fp16 row per edge (16B/lane dwordx4). One VMEM
// instruction covers 4 edges; unroll 4 -> 16 edges in flight per wave.
// Packed csr_ew gives {col, weight} in one sequential 8B load.

__global__ __launch_bounds__(256) void agg128_kernel(const _Float16* __restrict__ tbl,
        const int2* __restrict__ csr_ew,
        const int* __restrict__ offset, const float* __restrict__ dis,
        const float* __restrict__ bias, _Float16* __restrict__ out, int N, int do_relu) {
    int node = blockIdx.x * 4 + (threadIdx.x >> 6);
    if (node >= N) return;
    int lane = threadIdx.x & 63;
    int g = lane >> 4;                  // edge group 0..3
    int col8 = (lane & 15) * 8;         // 8 halves = 16B per lane
    float dn = dis[node];

    half8v sv = *(const half8v*)&tbl[(size_t)node * 128 + col8];
    float sw = (g == 0) ? dn * dn : 0.0f;
    float acc[8];
#pragma unroll
    for (int q = 0; q < 8; ++q) acc[q] = sw * (float)sv[q];

    int s = offset[node], e = offset[node + 1];
    int j = s + g;
    for (; j + 12 < e; j += 16) {       // 16 edges in flight per wave
        int2 e0 = csr_ew[j];
        int2 e1 = csr_ew[j + 4];
        int2 e2 = csr_ew[j + 8];
        int2 e3 = csr_ew[j + 12];
        half8v v0 = *(const half8v*)&tbl[(size_t)e0.x * 128 + col8];
        half8v v1 = *(const half8v*)&tbl[(size_t)e1.x * 128 + col8];
        half8v v2 = *(const half8v*)&tbl[(size_t)e2.x * 128 + col8];
        half8v v3 = *(const half8v*)&tbl[(size_t)e3.x * 128 + col8];
        float w0 = __int_as_float(e0.y);
        float w1 = __int_as_float(e1.y);
        float w2 = __int_as_float(e2.y);
        float w3 = __int_as_float(e3.y);
#pragma unroll
        for (int q = 0; q < 8; ++q) {
            acc[q] = fmaf(w0, (float)v0[q], acc[q]);
            acc[q] = fmaf(w1, (float)v1[q], acc[q]);
            acc[q] = fmaf(w2, (float)v2[q], acc[q]);
            acc[q] = fmaf(w3, (float)v3[q], acc[q]);
        }
    }
    for (; j < e; j += 4) {
        int2 ew = csr_ew[j];
        half8v v = *(const half8v*)&tbl[(size_t)ew.x * 128 + col8];
        float w = __int_as_float(ew.y);
#pragma unroll
        for (int q = 0; q < 8; ++q) acc[q] = fmaf(w, (float)v[q], acc[q]);
    }
    // reduce across the 4 groups
#pragma unroll
    for (int q = 0; q < 8; ++q) {
        acc[q] += __shfl_xor(acc[q], 16);
        acc[q] += __shfl_xor(acc[q], 32);
    }
    if (g == 0) {
        float4 b0 = *(const float4*)&bias[col8];
        float4 b1 = *(const float4*)&bias[col8 + 4];
        float o[8] = {acc[0] + b0.x, acc[1] + b0.y, acc[2] + b0.z, acc[3] + b0.w,
                      acc[4] + b1.x, acc[5] + b1.y, acc[6] + b1.z, acc[7] + b1.w};
        half8v ho;
#pragma unroll
        for (int q = 0; q < 8; ++q) {
            float v = do_relu ? fmaxf(o[q], 0.f) : o[q];
            ho[q] = (_Float16)v;
        }
        *(half8v*)&out[(size_t)node * 128 + col8] = ho;
    }
}

// ------- aggregation (16 wide) + bias + log_softmax: 16 lanes per node -------

__global__ __launch_bounds__(256) void agg16_ls_kernel(const float* __restrict__ t2,
        const int2* __restrict__ csr_ew,
        const int* __restrict__ offset, const float* __restrict__ dis,
        const float* __restrict__ b2, float* __restrict__ out, int N) {
    int gid = blockIdx.x * 256 + threadIdx.x;
    int node = gid >> 4;
    int c = gid & 15;
    if (node >= N) return;
    float dn = dis[node];
    float acc = dn * dn * t2[(size_t)node * 16 + c];
    int s = offset[node], e = offset[node + 1];
    for (int j = s; j < e; ++j) {
        int2 ew = csr_ew[j];
        acc = fmaf(__int_as_float(ew.y), t2[(size_t)ew.x * 16 + c], acc);
    }
    float v = acc + b2[c];
    float m = v;
#pragma unroll
    for (int o = 1; o < 16; o <<= 1) m = fmaxf(m, __shfl_xor(m, o, 16));
    float ex = expf(v - m);
    float ssum = ex;
#pragma unroll
    for (int o = 1; o < 16; o <<= 1) ssum += __shfl_xor(ssum, o, 16);
    out[(size_t)node * 16 + c] = v - m - logf(ssum);
}

// ---------------------------------- launch ----------------------------------

extern "C" void kernel_launch(void* const* d_in, const int* in_sizes, int n_in,
                              void* d_out, int out_size, void* d_ws, size_t ws_size,
                              hipStream_t stream) {
    const float* x  = (const float*)d_in[0];
    const int*   ei = (const int*)d_in[1];
    const float* W0 = (const float*)d_in[2];
    const float* b0 = (const float*)d_in[3];
    const float* W1 = (const float*)d_in[4];
    const float* b1 = (const float*)d_in[5];
    const float* W2 = (const float*)d_in[6];
    const float* b2 = (const float*)d_in[7];
    int N = in_sizes[0] / 128;
    int E = in_sizes[1] / 2;
    int PART = (N + 7) / 8;
    float* out = (float*)d_out;

    char* ws = (char*)d_ws;
    size_t off = 0;
    auto alloc = [&](size_t bytes) -> void* {
        void* p = ws + off;
        off = (off + bytes + 255) & ~(size_t)255;
        return p;
    };
    _Float16* t16  = (_Float16*)alloc((size_t)N * 128 * 2);
    _Float16* tB16 = (_Float16*)alloc((size_t)N * 128 * 2);
    float* t2      = (float*)alloc((size_t)N * 16 * 4);
    int*   cnt8    = (int*)alloc((size_t)N * 8 * 4);
    int*   offs    = (int*)alloc((size_t)(N + 1) * 4);
    int*   cursor  = (int*)alloc((size_t)N * 4);
    int*   blksum  = (int*)alloc(64 * 4);
    float* dis     = (float*)alloc((size_t)N * 4);
    int2*  csr_ew  = (int2*)alloc((size_t)E * 8);
    _Float16* Wt0  = (_Float16*)alloc(128 * 128 * 2);
    _Float16* Wt1  = (_Float16*)alloc(128 * 128 * 2);

    int n4 = (int)(((size_t)N * 8) / 4);
    setup_kernel<<<400, 256, 0, stream>>>(W0, W1, Wt0, Wt1, (int4*)cnt8, n4);

    int nchunk = (E + 255) / 256;
    int nb = (N + 1023) / 1024;   // 49 for N=50000 (must be <= 64)
    count_kernel<<<nchunk, 256, 0, stream>>>(ei, cnt8, N, E);
    scan1_kernel<<<nb, 256, 0, stream>>>(cnt8, offs, blksum, dis, N);
    scan23_kernel<<<(N + 255) / 256, 256, 0, stream>>>(offs, cursor, blksum, nb, N, E);
    fill_kernel<<<nchunk * 8, 256, 0, stream>>>(ei, E, PART, cursor, dis, csr_ew);

    int gemm_blocks = (N + 63) / 64;
    int agg_blocks  = (N + 3) / 4;

    gemm_mfma<1><<<gemm_blocks, 256, 0, stream>>>(x, Wt0, t16, N);
    agg128_kernel<<<agg_blocks, 256, 0, stream>>>(t16, csr_ew, offs, dis, b0, tB16, N, 1);
    gemm_mfma<0><<<gemm_blocks, 256, 0, stream>>>(tB16, Wt1, t16, N);
    agg128_kernel<<<agg_blocks, 256, 0, stream>>>(t16, csr_ew, offs, dis, b1, tB16, N, 1);
    gemm_nk16<<<(N + 31) / 32, 256, 0, stream>>>(tB16, W2, t2, N);
    agg16_ls_kernel<<<(int)(((size_t)N * 16 + 255) / 256), 256, 0, stream>>>(
        t2, csr_ew, offs, dis, b2, out, N);
}